// Round 2
// baseline (336.267 us; speedup 1.0000x reference)
//
#include <hip/hip_runtime.h>
#include <hip/hip_cooperative_groups.h>
#include <math.h>

namespace cg = cooperative_groups;

#define NN 50000
#define NE 800000
#define CD 128
#define NTILE 1563       // (NN+31)/32
#define OVCAP 65536      // overflow list capacity (deg>64 practically never happens)

typedef __attribute__((ext_vector_type(8))) short short8;
typedef __attribute__((ext_vector_type(4))) float f32x4;
typedef unsigned long long ull;

// ---------------- helpers ----------------

__device__ inline unsigned pack2bf(float lo, float hi) {
    unsigned a = __float_as_uint(lo), b = __float_as_uint(hi);
    a = (a + 0x7fffu + ((a >> 16) & 1u)) >> 16;
    b = (b + 0x7fffu + ((b >> 16) & 1u)) & 0xffff0000u;
    return a | b;
}

__device__ inline unsigned short f2bf(float f) {
    unsigned u = __float_as_uint(f);
    return (unsigned short)((u + 0x7fffu + ((u >> 16) & 1u)) >> 16);
}

__device__ inline void fmax8(float* m, uint4 v) {
    m[0] = fmaxf(m[0], __uint_as_float(v.x << 16));
    m[1] = fmaxf(m[1], __uint_as_float(v.x & 0xffff0000u));
    m[2] = fmaxf(m[2], __uint_as_float(v.y << 16));
    m[3] = fmaxf(m[3], __uint_as_float(v.y & 0xffff0000u));
    m[4] = fmaxf(m[4], __uint_as_float(v.z << 16));
    m[5] = fmaxf(m[5], __uint_as_float(v.z & 0xffff0000u));
    m[6] = fmaxf(m[6], __uint_as_float(v.w << 16));
    m[7] = fmaxf(m[7], __uint_as_float(v.w & 0xffff0000u));
}

// ---------------- single cooperative kernel ----------------
// Phase A: bucket-CSR scatter + x->bf16 cast + W transpose (parity-staggered).
// grid.sync()
// Phase B: per 32-row tile: gather+max -> LDS A-tile -> MFMA GEMM.

__global__ __launch_bounds__(256, 4) void mono_k(const int* __restrict__ ei,
                                                 const float* __restrict__ x,
                                                 const float* __restrict__ W,
                                                 const float* __restrict__ bias,
                                                 float* __restrict__ out,
                                                 int* __restrict__ cnt,
                                                 unsigned short* __restrict__ bkt,
                                                 unsigned* __restrict__ ovl,
                                                 unsigned* __restrict__ xb,
                                                 unsigned short* __restrict__ wt) {
    __shared__ unsigned short amx[32][136];  // maxdiff bf16 A-tile, pitch 272 B

    int t = threadIdx.x;
    int tid0 = blockIdx.x * 256 + t;
    int gsz = gridDim.x * 256;
    int phase = blockIdx.x & 1;

    // ---- phase A ----
    for (int p = 0; p < 2; p++) {
        if ((p ^ phase) == 0) {
            // scatter slice
            for (int e = tid0; e < NE; e += gsz) {
                int s = ei[e];
                int d = ei[NE + e];
                int k = atomicAdd(&cnt[d], 1);
                if (k < 64) {
                    bkt[(size_t)d * 64 + k] = (unsigned short)s;
                } else {
                    unsigned oi = atomicAdd((unsigned*)&cnt[NN], 1u);
                    if (oi < OVCAP) ovl[oi] = ((unsigned)d << 16) | (unsigned)s;
                }
            }
        } else {
            // x -> bf16 slice
            for (int i = tid0; i < NN * CD / 4; i += gsz) {
                float4 v = ((const float4*)x)[i];
                uint2 r;
                r.x = pack2bf(v.x, v.y);
                r.y = pack2bf(v.z, v.w);
                ((uint2*)xb)[i] = r;
            }
        }
    }
    // W -> transposed bf16 wt[n][k]
    for (int i = tid0; i < 2 * CD * CD; i += gsz) {
        int n = i >> 8, k = i & 255;
        wt[(size_t)n * 256 + k] = f2bf(W[(size_t)k * 128 + n]);
    }

    cg::this_grid().sync();

    // ---- phase B: grid-stride over 32-row tiles ----
    int w = t >> 6, lane = t & 63;
    int q = lane >> 4, c = lane & 15;
    int mm = lane & 15, g = lane >> 4;
    int rt = w & 1, ch = w >> 1;

    for (int tile = blockIdx.x; tile < NTILE; tile += gridDim.x) {
        int nbase = tile * 32;

        // gather + max
#pragma unroll 1
        for (int j = 0; j < 2; j++) {
            int ln = w * 8 + j * 4 + q;
            int node = nbase + ln;
            int cntv = (node < NN) ? cnt[node] : 0;
            int cn = min(cntv, 64);
            const unsigned short* brow = bkt + (size_t)node * 64;
            float m[8];
#pragma unroll
            for (int i = 0; i < 8; i++) m[i] = -INFINITY;

            for (int base = 0; base < cn; base += 8) {
                uint4 pk = *(const uint4*)(brow + base);
                int s0 = (int)(pk.x & 0xffffu), s1 = (int)(pk.x >> 16);
                int s2 = (int)(pk.y & 0xffffu), s3 = (int)(pk.y >> 16);
                int s4 = (int)(pk.z & 0xffffu), s5 = (int)(pk.z >> 16);
                int s6 = (int)(pk.w & 0xffffu), s7 = (int)(pk.w >> 16);
                if (base + 8 <= cn) {            // fast path: 8 loads in flight
                    fmax8(m, *(const uint4*)(xb + (size_t)s0 * 64 + c * 4));
                    fmax8(m, *(const uint4*)(xb + (size_t)s1 * 64 + c * 4));
                    fmax8(m, *(const uint4*)(xb + (size_t)s2 * 64 + c * 4));
                    fmax8(m, *(const uint4*)(xb + (size_t)s3 * 64 + c * 4));
                    fmax8(m, *(const uint4*)(xb + (size_t)s4 * 64 + c * 4));
                    fmax8(m, *(const uint4*)(xb + (size_t)s5 * 64 + c * 4));
                    fmax8(m, *(const uint4*)(xb + (size_t)s6 * 64 + c * 4));
                    fmax8(m, *(const uint4*)(xb + (size_t)s7 * 64 + c * 4));
                } else {
                    if (base + 0 < cn) fmax8(m, *(const uint4*)(xb + (size_t)s0 * 64 + c * 4));
                    if (base + 1 < cn) fmax8(m, *(const uint4*)(xb + (size_t)s1 * 64 + c * 4));
                    if (base + 2 < cn) fmax8(m, *(const uint4*)(xb + (size_t)s2 * 64 + c * 4));
                    if (base + 3 < cn) fmax8(m, *(const uint4*)(xb + (size_t)s3 * 64 + c * 4));
                    if (base + 4 < cn) fmax8(m, *(const uint4*)(xb + (size_t)s4 * 64 + c * 4));
                    if (base + 5 < cn) fmax8(m, *(const uint4*)(xb + (size_t)s5 * 64 + c * 4));
                    if (base + 6 < cn) fmax8(m, *(const uint4*)(xb + (size_t)s6 * 64 + c * 4));
                    if (base + 7 < cn) fmax8(m, *(const uint4*)(xb + (size_t)s7 * 64 + c * 4));
                }
            }
            // overflow fallback (degree > 64): practically never taken
            if (cntv > 64) {
                unsigned no = (unsigned)cnt[NN];
                if (no > OVCAP) no = OVCAP;
                for (unsigned i2 = 0; i2 < no; i2++) {
                    unsigned u = ovl[i2];
                    if ((int)(u >> 16) == node)
                        fmax8(m, *(const uint4*)(xb + (size_t)(u & 0xffffu) * 64 + c * 4));
                }
            }
            uint4 r = make_uint4(0u, 0u, 0u, 0u);
            if (cntv > 0) {                       // implies node < NN
                uint4 xd = *(const uint4*)(xb + (size_t)node * 64 + c * 4);
                float d0 = m[0] - __uint_as_float(xd.x << 16);
                float d1 = m[1] - __uint_as_float(xd.x & 0xffff0000u);
                float d2 = m[2] - __uint_as_float(xd.y << 16);
                float d3 = m[3] - __uint_as_float(xd.y & 0xffff0000u);
                float d4 = m[4] - __uint_as_float(xd.z << 16);
                float d5 = m[5] - __uint_as_float(xd.z & 0xffff0000u);
                float d6 = m[6] - __uint_as_float(xd.w << 16);
                float d7 = m[7] - __uint_as_float(xd.w & 0xffff0000u);
                r.x = pack2bf(d0, d1);
                r.y = pack2bf(d2, d3);
                r.z = pack2bf(d4, d5);
                r.w = pack2bf(d6, d7);
            }
            *(uint4*)&amx[ln][c * 8] = r;
        }
        __syncthreads();

        // MFMA GEMM (verified layout)
        int r0 = nbase + rt * 16;
        int row = r0 + mm;
        bool rowok = row < NN;

        f32x4 acc[4];
#pragma unroll
        for (int ct = 0; ct < 4; ct++) {
            float bv = bias[ch * 64 + ct * 16 + mm];
            acc[ct] = (f32x4){bv, bv, bv, bv};
        }

        const short* xbs = (const short*)xb;
#pragma unroll
        for (int kc = 0; kc < 8; kc++) {
            int k0 = kc * 32;
            short8 a;
            if (kc < 4) {
                a = (short8){0, 0, 0, 0, 0, 0, 0, 0};
                if (rowok) a = *(const short8*)(xbs + (size_t)row * 128 + k0 + g * 8);
            } else {
                a = *(const short8*)&amx[rt * 16 + mm][(k0 - 128) + g * 8];
            }
#pragma unroll
            for (int ct = 0; ct < 4; ct++) {
                short8 b = *(const short8*)(wt + (size_t)(ch * 64 + ct * 16 + mm) * 256 + k0 + g * 8);
                acc[ct] = __builtin_amdgcn_mfma_f32_16x16x32_bf16(a, b, acc[ct], 0, 0, 0);
            }
        }

#pragma unroll
        for (int ct = 0; ct < 4; ct++) {
#pragma unroll
            for (int i = 0; i < 4; i++) {
                int rr = r0 + g * 4 + i;
                if (rr < NN) out[(size_t)rr * 128 + ch * 64 + ct * 16 + mm] = acc[ct][i];
            }
        }
        __syncthreads();   // amx reused next tile
    }
}

// ---------------- launch ----------------

extern "C" void kernel_launch(void* const* d_in, const int* in_sizes, int n_in,
                              void* d_out, int out_size, void* d_ws, size_t ws_size,
                              hipStream_t stream) {
    const float* x = (const float*)d_in[0];
    const int* ei = (const int*)d_in[1];     // (2, E): [0..E)=src, [E..2E)=dst
    const float* W = (const float*)d_in[2];  // (256, 128) row-major
    const float* bias = (const float*)d_in[3];
    float* out = (float*)d_out;

    // Workspace layout (ints). Total = 4,931,936 ints = 19.73 MB.
    int* wsi = (int*)d_ws;
    int* cnt = wsi;                                          // 50016 ints (cnt[NN] = overflow count)
    unsigned short* bkt = (unsigned short*)(wsi + 50016);    // 3.2M ush = 1,600,000 ints (16B-aligned rows)
    unsigned* xb = (unsigned*)(wsi + 1650016);               // 3,200,000 uints (16B-aligned)
    unsigned short* wt = (unsigned short*)(wsi + 4850016);   // 32768 ush = 16384 ints
    unsigned* ovl = (unsigned*)(wsi + 4866400);              // 65536 uints

    // Co-resident grid size for cooperative launch (cached host-side).
    static int gridBlocks = 0;
    if (gridBlocks == 0) {
        int perCU = 0, numCU = 0;
        hipOccupancyMaxActiveBlocksPerMultiprocessor(&perCU, (const void*)mono_k, 256, 0);
        hipDeviceGetAttribute(&numCU, hipDeviceAttributeMultiprocessorCount, 0);
        long gb = (long)perCU * (long)numCU;
        if (gb < 256) gb = 1024;     // fallback
        if (gb > 2048) gb = 2048;
        gridBlocks = (int)gb;
    }

    hipMemsetAsync(cnt, 0, 50016 * sizeof(int), stream);     // cnt = 0, ovc = 0

    void* args[] = {(void*)&ei, (void*)&x, (void*)&W, (void*)&bias, (void*)&out,
                    (void*)&cnt, (void*)&bkt, (void*)&ovl, (void*)&xb, (void*)&wt};
    hipLaunchCooperativeKernel((void*)mono_k, dim3(gridBlocks), dim3(256), args, 0, stream);
}

// Round 3
// 189.499 us; speedup vs baseline: 1.7745x; 1.7745x over previous
//
#include <hip/hip_runtime.h>
#include <math.h>

#define NN 50000
#define NE 800000
#define CD 128
#define PB 3200          // prep blocks (grid-stride)
#define OVCAP 65536      // overflow list capacity (deg>64 practically never happens)

typedef __attribute__((ext_vector_type(8))) short short8;
typedef __attribute__((ext_vector_type(4))) float f32x4;

// ---------------- helpers ----------------

__device__ inline unsigned pack2bf(float lo, float hi) {
    unsigned a = __float_as_uint(lo), b = __float_as_uint(hi);
    a = (a + 0x7fffu + ((a >> 16) & 1u)) >> 16;
    b = (b + 0x7fffu + ((b >> 16) & 1u)) & 0xffff0000u;
    return a | b;
}

__device__ inline unsigned short f2bf(float f) {
    unsigned u = __float_as_uint(f);
    return (unsigned short)((u + 0x7fffu + ((u >> 16) & 1u)) >> 16);
}

__device__ inline void fmax8(float* m, uint4 v) {
    m[0] = fmaxf(m[0], __uint_as_float(v.x << 16));
    m[1] = fmaxf(m[1], __uint_as_float(v.x & 0xffff0000u));
    m[2] = fmaxf(m[2], __uint_as_float(v.y << 16));
    m[3] = fmaxf(m[3], __uint_as_float(v.y & 0xffff0000u));
    m[4] = fmaxf(m[4], __uint_as_float(v.z << 16));
    m[5] = fmaxf(m[5], __uint_as_float(v.z & 0xffff0000u));
    m[6] = fmaxf(m[6], __uint_as_float(v.w << 16));
    m[7] = fmaxf(m[7], __uint_as_float(v.w & 0xffff0000u));
}

// ---------------- prep: bucket-CSR scatter + bf16 casts (round-1 verbatim) ---

__global__ __launch_bounds__(256) void prep_k(const int* __restrict__ ei,
                                              const float* __restrict__ x,
                                              const float* __restrict__ W,
                                              int* __restrict__ cnt,
                                              unsigned short* __restrict__ bkt,
                                              unsigned* __restrict__ ovl,
                                              unsigned* __restrict__ xb,
                                              unsigned short* __restrict__ wt) {
    int tid0 = blockIdx.x * 256 + threadIdx.x;
    int phase = blockIdx.x & 1;

    for (int p = 0; p < 2; p++) {
        if ((p ^ phase) == 0) {
            // scatter slice
            for (int e = tid0; e < NE; e += PB * 256) {
                int s = ei[e];
                int d = ei[NE + e];
                int k = atomicAdd(&cnt[d], 1);
                if (k < 64) {
                    bkt[(size_t)d * 64 + k] = (unsigned short)s;
                } else {
                    unsigned oi = atomicAdd((unsigned*)&cnt[NN], 1u);
                    if (oi < OVCAP) ovl[oi] = ((unsigned)d << 16) | (unsigned)s;
                }
            }
        } else {
            // x -> bf16 slice
            for (int i = tid0; i < NN * CD / 4; i += PB * 256) {
                float4 v = ((const float4*)x)[i];
                uint2 r;
                r.x = pack2bf(v.x, v.y);
                r.y = pack2bf(v.z, v.w);
                ((uint2*)xb)[i] = r;
            }
        }
    }
    // W -> transposed bf16 wt[n][k]
    for (int i = tid0; i < 2 * CD * CD; i += PB * 256) {
        int n = i >> 8, k = i & 255;
        wt[(size_t)n * 256 + k] = f2bf(W[(size_t)k * 128 + n]);
    }
}

// ---------------- gather: 2-wave blocks, 8 nodes/block, no barriers ----------
// Each 16-lane quarter owns one node; 8 row-loads in flight on the fast path.
// Result (maxdiff bf16, 256 B/node) is written into the UNUSED second half of
// the out row (out rows are 512 B; final C overwrites everything in gemm_k).

__global__ __launch_bounds__(128) void gather_k(const unsigned* __restrict__ xb,
                                                const int* __restrict__ cnt,
                                                const unsigned short* __restrict__ bkt,
                                                const unsigned* __restrict__ ovl,
                                                unsigned* __restrict__ outu) {
    int t = threadIdx.x;
    int q = t >> 4, c = t & 15;
    int node = blockIdx.x * 8 + q;           // 6250*8 = 50000 exactly
    int cntv = cnt[node];
    int cn = min(cntv, 64);
    const unsigned short* brow = bkt + (size_t)node * 64;

    float m[8];
#pragma unroll
    for (int i = 0; i < 8; i++) m[i] = -INFINITY;

    for (int base = 0; base < cn; base += 8) {
        uint4 pk = *(const uint4*)(brow + base);
        int s0 = (int)(pk.x & 0xffffu), s1 = (int)(pk.x >> 16);
        int s2 = (int)(pk.y & 0xffffu), s3 = (int)(pk.y >> 16);
        int s4 = (int)(pk.z & 0xffffu), s5 = (int)(pk.z >> 16);
        int s6 = (int)(pk.w & 0xffffu), s7 = (int)(pk.w >> 16);
        if (base + 8 <= cn) {            // fast path: 8 loads in flight
            fmax8(m, *(const uint4*)(xb + (size_t)s0 * 64 + c * 4));
            fmax8(m, *(const uint4*)(xb + (size_t)s1 * 64 + c * 4));
            fmax8(m, *(const uint4*)(xb + (size_t)s2 * 64 + c * 4));
            fmax8(m, *(const uint4*)(xb + (size_t)s3 * 64 + c * 4));
            fmax8(m, *(const uint4*)(xb + (size_t)s4 * 64 + c * 4));
            fmax8(m, *(const uint4*)(xb + (size_t)s5 * 64 + c * 4));
            fmax8(m, *(const uint4*)(xb + (size_t)s6 * 64 + c * 4));
            fmax8(m, *(const uint4*)(xb + (size_t)s7 * 64 + c * 4));
        } else {
            if (base + 0 < cn) fmax8(m, *(const uint4*)(xb + (size_t)s0 * 64 + c * 4));
            if (base + 1 < cn) fmax8(m, *(const uint4*)(xb + (size_t)s1 * 64 + c * 4));
            if (base + 2 < cn) fmax8(m, *(const uint4*)(xb + (size_t)s2 * 64 + c * 4));
            if (base + 3 < cn) fmax8(m, *(const uint4*)(xb + (size_t)s3 * 64 + c * 4));
            if (base + 4 < cn) fmax8(m, *(const uint4*)(xb + (size_t)s4 * 64 + c * 4));
            if (base + 5 < cn) fmax8(m, *(const uint4*)(xb + (size_t)s5 * 64 + c * 4));
            if (base + 6 < cn) fmax8(m, *(const uint4*)(xb + (size_t)s6 * 64 + c * 4));
            if (base + 7 < cn) fmax8(m, *(const uint4*)(xb + (size_t)s7 * 64 + c * 4));
        }
    }
    // overflow fallback (degree > 64): practically never taken
    if (cntv > 64) {
        unsigned no = (unsigned)cnt[NN];
        if (no > OVCAP) no = OVCAP;
        for (unsigned i2 = 0; i2 < no; i2++) {
            unsigned u = ovl[i2];
            if ((int)(u >> 16) == node)
                fmax8(m, *(const uint4*)(xb + (size_t)(u & 0xffffu) * 64 + c * 4));
        }
    }
    uint4 r = make_uint4(0u, 0u, 0u, 0u);
    if (cntv > 0) {
        uint4 xd = *(const uint4*)(xb + (size_t)node * 64 + c * 4);
        float d0 = m[0] - __uint_as_float(xd.x << 16);
        float d1 = m[1] - __uint_as_float(xd.x & 0xffff0000u);
        float d2 = m[2] - __uint_as_float(xd.y << 16);
        float d3 = m[3] - __uint_as_float(xd.y & 0xffff0000u);
        float d4 = m[4] - __uint_as_float(xd.z << 16);
        float d5 = m[5] - __uint_as_float(xd.z & 0xffff0000u);
        float d6 = m[6] - __uint_as_float(xd.w << 16);
        float d7 = m[7] - __uint_as_float(xd.w & 0xffff0000u);
        r.x = pack2bf(d0, d1);
        r.y = pack2bf(d2, d3);
        r.z = pack2bf(d4, d5);
        r.w = pack2bf(d6, d7);
    }
    *(uint4*)(outu + (size_t)node * 128 + 64 + c * 4) = r;
}

// ---------------- GEMM: 32-row tiles, A preloaded to regs, then MFMA ---------
// A = [xb(row) | amx(row)] where amx lives in the second half of the out row.
// Barrier after A-preload: C writes overwrite the amx region other waves read.

__global__ __launch_bounds__(256) void gemm_k(const unsigned* __restrict__ xb,
                                              const unsigned* __restrict__ amxu,
                                              const short* __restrict__ wt,
                                              const float* __restrict__ bias,
                                              float* __restrict__ out) {
    int t = threadIdx.x;
    int w = t >> 6, lane = t & 63;
    int mm = lane & 15, g = lane >> 4;
    int rt = w & 1, ch = w >> 1;
    int nbase = blockIdx.x * 32;
    int r0 = nbase + rt * 16;
    int row = r0 + mm;
    bool rowok = row < NN;

    uint4 afr[8];
#pragma unroll
    for (int kc = 0; kc < 4; kc++)
        afr[kc] = rowok ? *(const uint4*)(xb + (size_t)row * 64 + kc * 16 + g * 4)
                        : make_uint4(0u, 0u, 0u, 0u);
#pragma unroll
    for (int kc = 4; kc < 8; kc++)
        afr[kc] = rowok ? *(const uint4*)(amxu + (size_t)row * 128 + 64 + (kc - 4) * 16 + g * 4)
                        : make_uint4(0u, 0u, 0u, 0u);

    __syncthreads();   // all A reads (incl. amx region of out) before C writes

    f32x4 acc[4];
#pragma unroll
    for (int ct = 0; ct < 4; ct++) {
        float bv = bias[ch * 64 + ct * 16 + mm];
        acc[ct] = (f32x4){bv, bv, bv, bv};
    }

#pragma unroll
    for (int kc = 0; kc < 8; kc++) {
        short8 a;
        __builtin_memcpy(&a, &afr[kc], 16);
#pragma unroll
        for (int ct = 0; ct < 4; ct++) {
            short8 b = *(const short8*)(wt + (size_t)(ch * 64 + ct * 16 + mm) * 256 + kc * 32 + g * 8);
            acc[ct] = __builtin_amdgcn_mfma_f32_16x16x32_bf16(a, b, acc[ct], 0, 0, 0);
        }
    }

#pragma unroll
    for (int ct = 0; ct < 4; ct++) {
#pragma unroll
        for (int i = 0; i < 4; i++) {
            int rr = r0 + g * 4 + i;
            if (rr < NN) out[(size_t)rr * 128 + ch * 64 + ct * 16 + mm] = acc[ct][i];
        }
    }
}

// ---------------- launch ----------------

extern "C" void kernel_launch(void* const* d_in, const int* in_sizes, int n_in,
                              void* d_out, int out_size, void* d_ws, size_t ws_size,
                              hipStream_t stream) {
    const float* x = (const float*)d_in[0];
    const int* ei = (const int*)d_in[1];     // (2, E): [0..E)=src, [E..2E)=dst
    const float* W = (const float*)d_in[2];  // (256, 128) row-major
    const float* bias = (const float*)d_in[3];
    float* out = (float*)d_out;

    // Workspace layout (ints). Total = 4,931,936 ints = 19.73 MB.
    int* wsi = (int*)d_ws;
    int* cnt = wsi;                                          // 50016 ints (cnt[NN] = overflow count)
    unsigned short* bkt = (unsigned short*)(wsi + 50016);    // 3.2M ush = 1,600,000 ints (16B-aligned rows)
    unsigned* xb = (unsigned*)(wsi + 1650016);               // 3,200,000 uints (16B-aligned)
    unsigned short* wt = (unsigned short*)(wsi + 4850016);   // 32768 ush = 16384 ints
    unsigned* ovl = (unsigned*)(wsi + 4866400);              // 65536 uints

    hipMemsetAsync(cnt, 0, 50016 * sizeof(int), stream);     // cnt = 0, ovc = 0

    prep_k<<<PB, 256, 0, stream>>>(ei, x, W, cnt, bkt, ovl, xb, wt);
    gather_k<<<NN / 8, 128, 0, stream>>>(xb, cnt, bkt, ovl, (unsigned*)out);
    gemm_k<<<(NN + 31) / 32, 256, 0, stream>>>(xb, (const unsigned*)out, (const short*)wt,
                                               bias, out);
}